// Round 11
// baseline (117.278 us; speedup 1.0000x reference)
//
#include <hip/hip_runtime.h>
#include <hip/hip_fp16.h>
#include <math.h>

#define NEG_SLOPE 0.2f

typedef _Float16 f16x8 __attribute__((ext_vector_type(8)));
typedef float f32x4 __attribute__((ext_vector_type(4)));

// ---------------------------------------------------------------------------
// Kernel 0: fused prep (blocks 0..63) + segment offsets (blocks 64..).
// ---------------------------------------------------------------------------
__global__ __launch_bounds__(256) void prep_seg_kernel(
    const float* __restrict__ W, __half* __restrict__ w16t,
    const int* __restrict__ dst, int* __restrict__ off, int E, int N)
{
    const int b = blockIdx.x;
    if (b < 64) {                                  // W fp32 [k][c] -> fp16 [c][k]
        int tid = b * 256 + threadIdx.x;
        int c = tid >> 7, k = tid & 127;
        w16t[c * 128 + k] = __float2half(W[k * 128 + c]);
        return;
    }
    int i = (b - 64) * 256 + threadIdx.x;
    if (i >= E) return;
    int d = dst[i];
    int prev = (i == 0) ? -1 : dst[i - 1];
    for (int n = prev + 1; n <= d; ++n) off[n] = i;
    if (i == E - 1) {
        for (int n = d + 1; n <= N; ++n) off[n] = E;
    }
}

// ---------------------------------------------------------------------------
// Kernel 1: proj — MFMA 16x16x32_f16, fused el/er epilogue, then i8
// row-quantization (per-row scale) written coalesced. feat8 = 12.8MB -> the
// aggregate's compulsory per-XCD fetch halves.
// ---------------------------------------------------------------------------
__global__ __launch_bounds__(256) void proj_kernel(
    const float* __restrict__ h, const __half* __restrict__ w16t,
    const float* __restrict__ attn_l, const float* __restrict__ attn_r,
    signed char* __restrict__ feat8, float* __restrict__ scale,
    float* __restrict__ el, float* __restrict__ er, int N)
{
    __shared__ __half hl[64 * 128];               // h tile, later reused as out tile
    __shared__ __half wl[128 * 128];
    const int t = threadIdx.x;
    const int nodeBase = blockIdx.x * 64;

#pragma unroll
    for (int i = 0; i < 8; ++i) {
        int ch = t + i * 256;                     // 2048 16B chunks
        int col = ch >> 4, k8 = ch & 15;
        uint4 v = *(const uint4*)(w16t + col * 128 + k8 * 8);
        int byte = col * 256 + k8 * 16;
        *(uint4*)((char*)wl + (byte ^ ((col & 7) << 4))) = v;
    }
#pragma unroll
    for (int i = 0; i < 8; ++i) {
        int slot = t + i * 256;                   // 2048 float4 slots
        int row = slot >> 5, c4 = slot & 31;
        int gn = nodeBase + row;
        float4 v = make_float4(0.f, 0.f, 0.f, 0.f);
        if (gn < N) v = *(const float4*)(h + (size_t)gn * 128 + c4 * 4);
        __half2 p0 = __floats2half2_rn(v.x, v.y);
        __half2 p1 = __floats2half2_rn(v.z, v.w);
        uint2 u = make_uint2(__builtin_bit_cast(unsigned int, p0),
                             __builtin_bit_cast(unsigned int, p1));
        int byte = row * 256 + c4 * 8;
        *(uint2*)((char*)hl + (byte ^ ((row & 7) << 4))) = u;
    }
    __syncthreads();

    const int l = t & 63, wave = t >> 6;
    const int arow = wave * 16 + (l & 15);
    const int kg = l >> 4;
    f32x4 acc[8];
#pragma unroll
    for (int i = 0; i < 8; ++i) acc[i] = (f32x4){0.f, 0.f, 0.f, 0.f};

#pragma unroll
    for (int kt = 0; kt < 4; ++kt) {
        const int kb = (kt * 32 + kg * 8) * 2;
        f16x8 a = *(const f16x8*)((const char*)hl +
                    ((arow * 256 + kb) ^ ((arow & 7) << 4)));
#pragma unroll
        for (int ct = 0; ct < 8; ++ct) {
            int bcol = ct * 16 + (l & 15);
            f16x8 b = *(const f16x8*)((const char*)wl +
                        ((bcol * 256 + kb) ^ ((bcol & 7) << 4)));
            acc[ct] = __builtin_amdgcn_mfma_f32_16x16x32_f16(a, b, acc[ct], 0, 0, 0);
        }
    }

    __syncthreads();                              // all waves done reading hl
    const int colLo = l & 15;
    const int rowHi = wave * 16 + (l >> 4) * 4;
#pragma unroll
    for (int ct = 0; ct < 8; ++ct) {
#pragma unroll
        for (int r = 0; r < 4; ++r) {
            int row = rowHi + r;
            int byte = row * 256 + (ct * 16 + colLo) * 2;
            *(__half*)((char*)hl + (byte ^ ((row & 7) << 4))) = __float2half(acc[ct][r]);
        }
    }

    // ---- fused el/er from acc regs
    float pl[4][4], pr[4][4];                     // [head][row]
#pragma unroll
    for (int hh = 0; hh < 4; ++hh) {
        float al0 = attn_l[hh * 32 + colLo];
        float al1 = attn_l[hh * 32 + 16 + colLo];
        float ar0 = attn_r[hh * 32 + colLo];
        float ar1 = attn_r[hh * 32 + 16 + colLo];
#pragma unroll
        for (int r = 0; r < 4; ++r) {
            pl[hh][r] = acc[2 * hh][r] * al0 + acc[2 * hh + 1][r] * al1;
            pr[hh][r] = acc[2 * hh][r] * ar0 + acc[2 * hh + 1][r] * ar1;
        }
    }
#pragma unroll
    for (int msk = 1; msk <= 8; msk <<= 1) {
#pragma unroll
        for (int hh = 0; hh < 4; ++hh)
#pragma unroll
            for (int r = 0; r < 4; ++r) {
                pl[hh][r] += __shfl_xor(pl[hh][r], msk);
                pr[hh][r] += __shfl_xor(pr[hh][r], msk);
            }
    }
    if (colLo == 0) {
#pragma unroll
        for (int r = 0; r < 4; ++r) {
            int node = nodeBase + rowHi + r;
            if (node < N) {
                *(float4*)(el + (size_t)node * 4) =
                    make_float4(pl[0][r], pl[1][r], pl[2][r], pl[3][r]);
                *(float4*)(er + (size_t)node * 4) =
                    make_float4(pr[0][r], pr[1][r], pr[2][r], pr[3][r]);
            }
        }
    }
    __syncthreads();                              // hl tile complete

    // ---- i8 row-quant: thread t -> row r=t>>2, quarter q=t&3 (32 cols)
    {
        const int r = t >> 2, q = t & 3;
        uint4 c4[4];
#pragma unroll
        for (int j = 0; j < 4; ++j) {
            int ch = r * 16 + q * 4 + j;          // 16B chunk index in row
            c4[j] = *(const uint4*)((const char*)hl + ((ch * 16) ^ ((r & 7) << 4)));
        }
        float mx = 1e-20f;                        // fp32 max-scan (no __hmax2 on ROCm 7.2)
#pragma unroll
        for (int j = 0; j < 4; ++j) {
            const __half2* hp = (const __half2*)&c4[j];
#pragma unroll
            for (int u = 0; u < 4; ++u) {
                float2 f = __half22float2(hp[u]);
                mx = fmaxf(mx, fmaxf(fabsf(f.x), fabsf(f.y)));
            }
        }
        mx = fmaxf(mx, __shfl_xor(mx, 1));        // reduce across 4 quarters
        mx = fmaxf(mx, __shfl_xor(mx, 2));
        const float qinv = 127.f / mx;
        const int node = nodeBase + r;
        if (q == 0 && node < N) scale[node] = mx * (1.f / 127.f);
        unsigned int outw[8];
#pragma unroll
        for (int j = 0; j < 4; ++j) {
            const __half2* hp = (const __half2*)&c4[j];
#pragma unroll
            for (int u = 0; u < 2; ++u) {
                float2 fa = __half22float2(hp[2 * u]);
                float2 fb = __half22float2(hp[2 * u + 1]);
                int i0 = __float2int_rn(fa.x * qinv) & 255;
                int i1 = __float2int_rn(fa.y * qinv) & 255;
                int i2 = __float2int_rn(fb.x * qinv) & 255;
                int i3 = __float2int_rn(fb.y * qinv) & 255;
                outw[j * 2 + u] = (unsigned)i0 | ((unsigned)i1 << 8) |
                                  ((unsigned)i2 << 16) | ((unsigned)i3 << 24);
            }
        }
        if (node < N) {
            uint4* d4 = (uint4*)(feat8 + (size_t)node * 128 + q * 32);
            d4[0] = make_uint4(outw[0], outw[1], outw[2], outw[3]);
            d4[1] = make_uint4(outw[4], outw[5], outw[6], outw[7]);
        }
    }
}

// ---------------------------------------------------------------------------
// Kernel 2: fused aggregate on i8 feat. One wave per node; lane l owns
// features 2l,2l+1 (head hm=l>>4). out = sum(w*scale[src]*q)/sum(w).
// Cooperative w (1 exp/lane/16 edges); dn via 4x shfl_xor class-reduce.
// Gathers are 128B/edge (ushort per lane), SGPR src addressing.
// ---------------------------------------------------------------------------
__global__ __launch_bounds__(256) void aggregate_kernel(
    const signed char* __restrict__ feat8, const float* __restrict__ scale,
    const float* __restrict__ el, const float* __restrict__ er,
    const int* __restrict__ off, const int* __restrict__ src,
    const float* __restrict__ bias, float* __restrict__ out, int N)
{
    const int wid = (int)((blockIdx.x * blockDim.x + threadIdx.x) >> 6);
    const int l = threadIdx.x & 63;
    if (wid >= N) return;
    const int n = __builtin_amdgcn_readfirstlane(wid);   // SGPR node id
    const int s = off[n];                                // s_load
    const int e = off[n + 1];                            // s_load
    const int f0 = 2 * l;
    const int hm = l >> 4;
    const float b0 = bias[f0], b1 = bias[f0 + 1];
    float* outp = out + (size_t)n * 128;
    if (s >= e) {
        outp[f0] = fmaxf(b0, 0.f);
        outp[f0 + 1] = fmaxf(b1, 0.f);
        return;
    }

    const float er_mine = er[n * 4 + hm];
    const float er_coop = er[n * 4 + (l & 3)];
    float ax = 0.f, ay = 0.f, dn = 0.f;

    int ei = s;
    for (; ei + 16 <= e; ei += 16) {
        int sv[16];
#pragma unroll
        for (int k = 0; k < 16; ++k) sv[k] = src[ei + k];        // s_loads
        // cooperative w: lane c -> edge c>>2, head c&3
        int svc = src[ei + (l >> 2)];                            // 1 line
        float scl = scale[svc];
        float sc = el[(size_t)svc * 4 + (l & 3)] + er_coop;
        sc = sc > 0.f ? sc : NEG_SLOPE * sc;
        float w = __expf(sc);
        float ws = w * scl;                                      // dequant folded
        unsigned short gg[16];
#pragma unroll
        for (int k = 0; k < 16; ++k)
            gg[k] = *(const unsigned short*)(feat8 + (size_t)sv[k] * 128 + f0);
        float dsum = w;                                          // class c&3 sum
        dsum += __shfl_xor(dsum, 4);
        dsum += __shfl_xor(dsum, 8);
        dsum += __shfl_xor(dsum, 16);
        dsum += __shfl_xor(dsum, 32);
        dn += __shfl(dsum, hm);
#pragma unroll
        for (int k = 0; k < 16; ++k) {
            float wsk = __shfl(ws, 4 * k + hm);
            int q0 = (int)(signed char)(gg[k] & 0xff);
            int q1 = (int)(signed char)(gg[k] >> 8);
            ax += wsk * (float)q0;
            ay += wsk * (float)q1;
        }
    }
    if (ei + 8 <= e) {
        int sv[8];
#pragma unroll
        for (int k = 0; k < 8; ++k) sv[k] = src[ei + k];
        int svc = src[ei + ((l >> 2) & 7)];
        float scl = scale[svc];
        float sc = el[(size_t)svc * 4 + (l & 3)] + er_coop;
        sc = sc > 0.f ? sc : NEG_SLOPE * sc;
        float w = __expf(sc);
        float ws = w * scl;
        unsigned short gg[8];
#pragma unroll
        for (int k = 0; k < 8; ++k)
            gg[k] = *(const unsigned short*)(feat8 + (size_t)sv[k] * 128 + f0);
        float dsum = w;                                          // lanes 0..31 cover 8 edges
        dsum += __shfl_xor(dsum, 4);
        dsum += __shfl_xor(dsum, 8);
        dsum += __shfl_xor(dsum, 16);
        dn += __shfl(dsum, hm);
#pragma unroll
        for (int k = 0; k < 8; ++k) {
            float wsk = __shfl(ws, 4 * k + hm);
            int q0 = (int)(signed char)(gg[k] & 0xff);
            int q1 = (int)(signed char)(gg[k] >> 8);
            ax += wsk * (float)q0;
            ay += wsk * (float)q1;
        }
        ei += 8;
    }
    for (; ei < e; ++ei) {                                       // <=7 tail edges
        int sv = src[ei];
        float sc = el[(size_t)sv * 4 + hm] + er_mine;
        sc = sc > 0.f ? sc : NEG_SLOPE * sc;
        float w = __expf(sc);
        float ws = w * scale[sv];
        unsigned short gg = *(const unsigned short*)(feat8 + (size_t)sv * 128 + f0);
        int q0 = (int)(signed char)(gg & 0xff);
        int q1 = (int)(signed char)(gg >> 8);
        dn += w;
        ax += ws * (float)q0;
        ay += ws * (float)q1;
    }
    const float inv = 1.f / dn;
    *(float2*)(outp + f0) = make_float2(fmaxf(ax * inv + b0, 0.f),
                                        fmaxf(ay * inv + b1, 0.f));
}

// ---------------------------------------------------------------------------
extern "C" void kernel_launch(void* const* d_in, const int* in_sizes, int n_in,
                              void* d_out, int out_size, void* d_ws, size_t ws_size,
                              hipStream_t stream)
{
    const float* h      = (const float*)d_in[0];
    const int*   src    = (const int*)d_in[1];
    const int*   dst    = (const int*)d_in[2];
    const float* W      = (const float*)d_in[3];
    const float* attn_l = (const float*)d_in[4];
    const float* attn_r = (const float*)d_in[5];
    const float* bias   = (const float*)d_in[6];
    const int N = in_sizes[0] / 128;
    const int E = in_sizes[1];
    float* out = (float*)d_out;

    // workspace (all offsets multiples of 16B)
    char* ws = (char*)d_ws;
    signed char* feat8 = (signed char*)ws;  ws += (size_t)N * 128;                 // 12.8MB
    float*  scale = (float*)ws;             ws += (size_t)N * sizeof(float);       // 0.4MB
    float*  el    = (float*)ws;             ws += (size_t)N * 4 * sizeof(float);   // 1.6MB
    float*  er    = (float*)ws;             ws += (size_t)N * 4 * sizeof(float);   // 1.6MB
    __half* w16t  = (__half*)ws;            ws += 128 * 128 * sizeof(__half);      // 32KB
    int*    off   = (int*)ws;

    hipLaunchKernelGGL(prep_seg_kernel, dim3(64 + (E + 255) / 256), dim3(256), 0, stream,
                       W, w16t, dst, off, E, N);
    hipLaunchKernelGGL(proj_kernel, dim3((N + 63) / 64), dim3(256), 0, stream,
                       h, w16t, attn_l, attn_r, feat8, scale, el, er, N);
    hipLaunchKernelGGL(aggregate_kernel, dim3((N + 3) / 4), dim3(256), 0, stream,
                       feat8, scale, el, er, off, src, bias, out, N);
}